// Round 1
// baseline (5856.773 us; speedup 1.0000x reference)
//
#include <hip/hip_runtime.h>

#define N_NODES 100000
#define N_EDGES 1600000
#define N_LABEL 200000
#define C_IN 128
#define C_HID 256
#define C_OUT 128

// ---------------------------------------------------------------------------
// Edge-parallel scatter: agg[dst][0:128] += feat[src][0:128]; optional deg.
// 32 lanes per edge, float4 per lane (128 ch).
// ---------------------------------------------------------------------------
template <bool ADD_DEG>
__global__ __launch_bounds__(256) void scatter_kernel(const int* __restrict__ src,
                                                      const int* __restrict__ dst,
                                                      const float* __restrict__ feat,
                                                      float* __restrict__ agg,
                                                      float* __restrict__ deg) {
  long long tid = (long long)blockIdx.x * 256 + threadIdx.x;
  int e = (int)(tid >> 5);
  int lane = (int)(tid & 31);
  if (e >= N_EDGES) return;
  int s = src[e];
  int d = dst[e];
  const float4 v = *(const float4*)&feat[(size_t)s * 128 + lane * 4];
  float* ap = &agg[(size_t)d * 128 + lane * 4];
  atomicAdd(ap + 0, v.x);
  atomicAdd(ap + 1, v.y);
  atomicAdd(ap + 2, v.z);
  atomicAdd(ap + 3, v.w);
  if (ADD_DEG && lane == 0) atomicAdd(&deg[d], 1.0f);
}

// ---------------------------------------------------------------------------
// Layer-1 fused GEMM: h = relu( (agg/deg) @ Wl1 + bl1 + x @ Wr1 )
// Virtual K = 256 (first 128 from normalized agg via Wl1, next 128 from x via
// Wr1). Tile 64x64, 256 threads, 4x4 per-thread register blocking.
// ---------------------------------------------------------------------------
__global__ __launch_bounds__(256) void l1_gemm(const float* __restrict__ agg,
                                               const float* __restrict__ deg,
                                               const float* __restrict__ x,
                                               const float* __restrict__ Wl,
                                               const float* __restrict__ Wr,
                                               const float* __restrict__ bias,
                                               float* __restrict__ h) {
  __shared__ float a_sh[32][68];  // transposed [k][m], pad 68 keeps 16B align
  __shared__ float w_sh[32][64];
  const int tid = threadIdx.x;
  const int row0 = blockIdx.x * 64;
  const int col0 = blockIdx.y * 64;
  const int tm = tid >> 4;   // 0..15
  const int tn = tid & 15;   // 0..15
  float acc[4][4] = {};

  for (int kc = 0; kc < 8; ++kc) {
    const int kk0 = kc * 32;
    const bool first = (kk0 < 128);
    const float* Asrc = first ? agg : x;
    const float* Wsrc = first ? Wl : Wr;
    const int kbase = first ? kk0 : (kk0 - 128);
    __syncthreads();
    // A tile: 64 rows x 32 k, store transposed
    {
      int r = tid >> 3;          // 0..31
      const int k4 = (tid & 7) * 4;
      for (int it = 0; it < 2; ++it, r += 32) {
        const int grow = row0 + r;
        float4 v = make_float4(0.f, 0.f, 0.f, 0.f);
        if (grow < N_NODES) {
          v = *(const float4*)&Asrc[(size_t)grow * 128 + kbase + k4];
          if (first) {
            const float rd = 1.0f / fmaxf(deg[grow], 1.0f);
            v.x *= rd; v.y *= rd; v.z *= rd; v.w *= rd;
          }
        }
        a_sh[k4 + 0][r] = v.x;
        a_sh[k4 + 1][r] = v.y;
        a_sh[k4 + 2][r] = v.z;
        a_sh[k4 + 3][r] = v.w;
      }
    }
    // W tile: 32 k x 64 n
    {
      int k = tid >> 4;          // 0..15
      const int n4 = (tid & 15) * 4;
      for (int it = 0; it < 2; ++it, k += 16) {
        *(float4*)&w_sh[k][n4] =
            *(const float4*)&Wsrc[(size_t)(kbase + k) * C_HID + col0 + n4];
      }
    }
    __syncthreads();
#pragma unroll
    for (int k = 0; k < 32; ++k) {
      const float4 va = *(const float4*)&a_sh[k][tm * 4];
      const float4 vb = *(const float4*)&w_sh[k][tn * 4];
      const float av[4] = {va.x, va.y, va.z, va.w};
      const float bv[4] = {vb.x, vb.y, vb.z, vb.w};
#pragma unroll
      for (int i = 0; i < 4; ++i)
#pragma unroll
        for (int j = 0; j < 4; ++j) acc[i][j] += av[i] * bv[j];
    }
  }
  // epilogue: + bias, relu
  const int gcol = col0 + tn * 4;
  const float4 b = *(const float4*)&bias[gcol];
  const float bb[4] = {b.x, b.y, b.z, b.w};
#pragma unroll
  for (int i = 0; i < 4; ++i) {
    const int grow = row0 + tm * 4 + i;
    if (grow >= N_NODES) break;
    float4 o;
    o.x = fmaxf(acc[i][0] + bb[0], 0.0f);
    o.y = fmaxf(acc[i][1] + bb[1], 0.0f);
    o.z = fmaxf(acc[i][2] + bb[2], 0.0f);
    o.w = fmaxf(acc[i][3] + bb[3], 0.0f);
    *(float4*)&h[(size_t)grow * C_HID + gcol] = o;
  }
}

// ---------------------------------------------------------------------------
// Generic GEMM on h [N x 256] @ W [256 x 128] -> out [N x 128]
// MODE 0: out = h @ W                     (p = h @ Wl2)
// MODE 1: out = h @ W + agg/deg + bias    (z = h @ Wr2 + aggn + bl2)
// ---------------------------------------------------------------------------
template <int MODE>
__global__ __launch_bounds__(256) void h_gemm(const float* __restrict__ A,
                                              const float* __restrict__ W,
                                              const float* __restrict__ bias,
                                              const float* __restrict__ agg,
                                              const float* __restrict__ deg,
                                              float* __restrict__ out) {
  __shared__ float a_sh[32][68];
  __shared__ float w_sh[32][64];
  const int tid = threadIdx.x;
  const int row0 = blockIdx.x * 64;
  const int col0 = blockIdx.y * 64;
  const int tm = tid >> 4;
  const int tn = tid & 15;
  float acc[4][4] = {};

  for (int kc = 0; kc < 8; ++kc) {
    const int kbase = kc * 32;
    __syncthreads();
    {
      int r = tid >> 3;
      const int k4 = (tid & 7) * 4;
      for (int it = 0; it < 2; ++it, r += 32) {
        const int grow = row0 + r;
        float4 v = make_float4(0.f, 0.f, 0.f, 0.f);
        if (grow < N_NODES)
          v = *(const float4*)&A[(size_t)grow * C_HID + kbase + k4];
        a_sh[k4 + 0][r] = v.x;
        a_sh[k4 + 1][r] = v.y;
        a_sh[k4 + 2][r] = v.z;
        a_sh[k4 + 3][r] = v.w;
      }
    }
    {
      int k = tid >> 4;
      const int n4 = (tid & 15) * 4;
      for (int it = 0; it < 2; ++it, k += 16) {
        *(float4*)&w_sh[k][n4] =
            *(const float4*)&W[(size_t)(kbase + k) * C_OUT + col0 + n4];
      }
    }
    __syncthreads();
#pragma unroll
    for (int k = 0; k < 32; ++k) {
      const float4 va = *(const float4*)&a_sh[k][tm * 4];
      const float4 vb = *(const float4*)&w_sh[k][tn * 4];
      const float av[4] = {va.x, va.y, va.z, va.w};
      const float bv[4] = {vb.x, vb.y, vb.z, vb.w};
#pragma unroll
      for (int i = 0; i < 4; ++i)
#pragma unroll
        for (int j = 0; j < 4; ++j) acc[i][j] += av[i] * bv[j];
    }
  }
  const int gcol = col0 + tn * 4;
  float bb[4] = {0.f, 0.f, 0.f, 0.f};
  if (MODE == 1) {
    const float4 b = *(const float4*)&bias[gcol];
    bb[0] = b.x; bb[1] = b.y; bb[2] = b.z; bb[3] = b.w;
  }
#pragma unroll
  for (int i = 0; i < 4; ++i) {
    const int grow = row0 + tm * 4 + i;
    if (grow >= N_NODES) break;
    float4 o;
    if (MODE == 1) {
      const float rd = 1.0f / fmaxf(deg[grow], 1.0f);
      const float4 ag = *(const float4*)&agg[(size_t)grow * C_OUT + gcol];
      o.x = acc[i][0] + bb[0] + ag.x * rd;
      o.y = acc[i][1] + bb[1] + ag.y * rd;
      o.z = acc[i][2] + bb[2] + ag.z * rd;
      o.w = acc[i][3] + bb[3] + ag.w * rd;
    } else {
      o.x = acc[i][0]; o.y = acc[i][1]; o.z = acc[i][2]; o.w = acc[i][3];
    }
    *(float4*)&out[(size_t)grow * C_OUT + gcol] = o;
  }
}

// ---------------------------------------------------------------------------
// Decode: out[e] = dot(z[lsrc[e]], z[ldst[e]]) over 128 ch. 32 lanes/edge.
// ---------------------------------------------------------------------------
__global__ __launch_bounds__(256) void dot_kernel(const int* __restrict__ ls,
                                                  const int* __restrict__ ld,
                                                  const float* __restrict__ z,
                                                  float* __restrict__ out) {
  long long tid = (long long)blockIdx.x * 256 + threadIdx.x;
  int e = (int)(tid >> 5);
  int lane = (int)(tid & 31);
  if (e >= N_LABEL) return;
  int a = ls[e], b = ld[e];
  const float4 va = *(const float4*)&z[(size_t)a * 128 + lane * 4];
  const float4 vb = *(const float4*)&z[(size_t)b * 128 + lane * 4];
  float p = va.x * vb.x + va.y * vb.y + va.z * vb.z + va.w * vb.w;
  p += __shfl_xor(p, 16, 32);
  p += __shfl_xor(p, 8, 32);
  p += __shfl_xor(p, 4, 32);
  p += __shfl_xor(p, 2, 32);
  p += __shfl_xor(p, 1, 32);
  if (lane == 0) out[e] = p;
}

extern "C" void kernel_launch(void* const* d_in, const int* in_sizes, int n_in,
                              void* d_out, int out_size, void* d_ws, size_t ws_size,
                              hipStream_t stream) {
  const float* x = (const float*)d_in[0];
  const int* ei = (const int*)d_in[1];       // [2, E]: src row, dst row
  const int* eli = (const int*)d_in[2];      // [2, L]
  const float* Wl1 = (const float*)d_in[3];
  const float* bl1 = (const float*)d_in[4];
  const float* Wr1 = (const float*)d_in[5];
  const float* Wl2 = (const float*)d_in[6];
  const float* bl2 = (const float*)d_in[7];
  const float* Wr2 = (const float*)d_in[8];
  float* out = (float*)d_out;

  const int* e_src = ei;
  const int* e_dst = ei + N_EDGES;
  const int* l_src = eli;
  const int* l_dst = eli + N_LABEL;

  char* ws = (char*)d_ws;
  const size_t AGG_BYTES = (size_t)N_NODES * 128 * 4;   // 51,200,000
  const size_t DEG_BYTES = (size_t)N_NODES * 4;         //    400,000
  const size_t H_BYTES = (size_t)N_NODES * C_HID * 4;   // 102,400,000
  float* agg = (float*)ws;
  float* deg = (float*)(ws + AGG_BYTES);
  float* h = (float*)(ws + AGG_BYTES + DEG_BYTES);
  float* p = (float*)(ws + AGG_BYTES + DEG_BYTES + H_BYTES);
  float* z = p;  // z overwrites p (p dead after second scatter)

  // 1. zero agg + deg (contiguous)
  hipMemsetAsync(agg, 0, AGG_BYTES + DEG_BYTES, stream);
  // 2. scatter x -> agg, count deg
  scatter_kernel<true><<<(int)(((long long)N_EDGES * 32) / 256), 256, 0, stream>>>(
      e_src, e_dst, x, agg, deg);
  // 3. h = relu(agg/deg @ Wl1 + bl1 + x @ Wr1)
  l1_gemm<<<dim3((N_NODES + 63) / 64, C_HID / 64), 256, 0, stream>>>(
      agg, deg, x, Wl1, Wr1, bl1, h);
  // 4. p = h @ Wl2
  h_gemm<0><<<dim3((N_NODES + 63) / 64, C_OUT / 64), 256, 0, stream>>>(
      h, Wl2, nullptr, nullptr, nullptr, p);
  // 5. re-zero agg
  hipMemsetAsync(agg, 0, AGG_BYTES, stream);
  // 6. scatter p -> agg
  scatter_kernel<false><<<(int)(((long long)N_EDGES * 32) / 256), 256, 0, stream>>>(
      e_src, e_dst, p, agg, deg);
  // 7. z = h @ Wr2 + agg/deg + bl2   (z aliases p)
  h_gemm<1><<<dim3((N_NODES + 63) / 64, C_OUT / 64), 256, 0, stream>>>(
      h, Wr2, bl2, agg, deg, z);
  // 8. decode
  dot_kernel<<<(int)(((long long)N_LABEL * 32) / 256), 256, 0, stream>>>(
      l_src, l_dst, z, out);
}

// Round 2
// 1048.384 us; speedup vs baseline: 5.5865x; 5.5865x over previous
//
#include <hip/hip_runtime.h>

#define N_NODES 100000
#define N_EDGES 1600000
#define N_LABEL 200000
#define C_IN 128
#define C_HID 256
#define C_OUT 128

// ---------------------------------------------------------------------------
// CSR build step 1: in-degree histogram.
// ---------------------------------------------------------------------------
__global__ __launch_bounds__(256) void hist_kernel(const int* __restrict__ dst,
                                                   int* __restrict__ counts) {
  int e = blockIdx.x * 256 + threadIdx.x;
  if (e < N_EDGES) atomicAdd(&counts[dst[e]], 1);
}

// ---------------------------------------------------------------------------
// CSR build step 2: exclusive scan of counts -> row_start[N+1]; also
// overwrite counts[] with the exclusive scan to serve as the fill cursor.
// Single block of 1024 threads; each owns a contiguous chunk.
// ---------------------------------------------------------------------------
__global__ __launch_bounds__(1024) void scan_kernel(int* __restrict__ counts,
                                                    int* __restrict__ row_start) {
  __shared__ int part[1024];
  const int t = threadIdx.x;
  const int CHUNK = (N_NODES + 1023) / 1024;  // 98
  const int lo = t * CHUNK;
  const int hi = min(lo + CHUNK, N_NODES);
  int sum = 0;
  for (int i = lo; i < hi; ++i) sum += counts[i];
  part[t] = sum;
  __syncthreads();
  for (int off = 1; off < 1024; off <<= 1) {
    int v = 0;
    if (t >= off) v = part[t - off];
    __syncthreads();
    if (t >= off) part[t] += v;
    __syncthreads();
  }
  int run = (t == 0) ? 0 : part[t - 1];  // exclusive prefix of this chunk
  for (int i = lo; i < hi; ++i) {
    const int c = counts[i];
    row_start[i] = run;
    counts[i] = run;  // cursor for fill_kernel
    run += c;
  }
  if (t == 1023) row_start[N_NODES] = run;  // == N_EDGES
}

// ---------------------------------------------------------------------------
// CSR build step 3: fill per-destination source lists.
// ---------------------------------------------------------------------------
__global__ __launch_bounds__(256) void fill_kernel(const int* __restrict__ src,
                                                   const int* __restrict__ dst,
                                                   int* __restrict__ cursor,
                                                   int* __restrict__ csr_src) {
  int e = blockIdx.x * 256 + threadIdx.x;
  if (e < N_EDGES) {
    const int pos = atomicAdd(&cursor[dst[e]], 1);
    csr_src[pos] = src[e];
  }
}

// ---------------------------------------------------------------------------
// Mean aggregation by gather: one 64-lane wave per node; each lane owns 2 of
// the 128 channels (float2). Per edge: one coalesced 512B row read. No atomics.
// Writes the MEAN directly (deg normalization folded in).
// ---------------------------------------------------------------------------
__global__ __launch_bounds__(256) void gather_mean(const int* __restrict__ row_start,
                                                   const int* __restrict__ csr_src,
                                                   const float* __restrict__ feat,
                                                   float* __restrict__ out) {
  const int wid = blockIdx.x * 4 + (threadIdx.x >> 6);
  const int lane = threadIdx.x & 63;
  if (wid >= N_NODES) return;
  const int s = row_start[wid];
  const int e = row_start[wid + 1];
  const int c0 = lane * 2;
  float2 acc0 = make_float2(0.f, 0.f);
  float2 acc1 = make_float2(0.f, 0.f);
  int j = s;
  for (; j + 1 < e; j += 2) {
    const int s0 = csr_src[j];
    const int s1 = csr_src[j + 1];
    const float2 v0 = *(const float2*)&feat[(size_t)s0 * 128 + c0];
    const float2 v1 = *(const float2*)&feat[(size_t)s1 * 128 + c0];
    acc0.x += v0.x; acc0.y += v0.y;
    acc1.x += v1.x; acc1.y += v1.y;
  }
  if (j < e) {
    const int s0 = csr_src[j];
    const float2 v0 = *(const float2*)&feat[(size_t)s0 * 128 + c0];
    acc0.x += v0.x; acc0.y += v0.y;
  }
  const float rd = 1.0f / fmaxf((float)(e - s), 1.0f);
  float2 o;
  o.x = (acc0.x + acc1.x) * rd;
  o.y = (acc0.y + acc1.y) * rd;
  *(float2*)&out[(size_t)wid * 128 + c0] = o;
}

// ---------------------------------------------------------------------------
// Layer-1 fused GEMM: h = relu( aggn @ Wl1 + bl1 + x @ Wr1 )   (aggn = mean)
// Virtual K = 256. Tile 64x64, 256 threads, 4x4 register blocking.
// ---------------------------------------------------------------------------
__global__ __launch_bounds__(256) void l1_gemm(const float* __restrict__ aggn,
                                               const float* __restrict__ x,
                                               const float* __restrict__ Wl,
                                               const float* __restrict__ Wr,
                                               const float* __restrict__ bias,
                                               float* __restrict__ h) {
  __shared__ float a_sh[32][68];
  __shared__ float w_sh[32][64];
  const int tid = threadIdx.x;
  const int row0 = blockIdx.x * 64;
  const int col0 = blockIdx.y * 64;
  const int tm = tid >> 4;
  const int tn = tid & 15;
  float acc[4][4] = {};

  for (int kc = 0; kc < 8; ++kc) {
    const int kk0 = kc * 32;
    const bool first = (kk0 < 128);
    const float* Asrc = first ? aggn : x;
    const float* Wsrc = first ? Wl : Wr;
    const int kbase = first ? kk0 : (kk0 - 128);
    __syncthreads();
    {
      int r = tid >> 3;
      const int k4 = (tid & 7) * 4;
      for (int it = 0; it < 2; ++it, r += 32) {
        const int grow = row0 + r;
        float4 v = make_float4(0.f, 0.f, 0.f, 0.f);
        if (grow < N_NODES)
          v = *(const float4*)&Asrc[(size_t)grow * 128 + kbase + k4];
        a_sh[k4 + 0][r] = v.x;
        a_sh[k4 + 1][r] = v.y;
        a_sh[k4 + 2][r] = v.z;
        a_sh[k4 + 3][r] = v.w;
      }
    }
    {
      int k = tid >> 4;
      const int n4 = (tid & 15) * 4;
      for (int it = 0; it < 2; ++it, k += 16) {
        *(float4*)&w_sh[k][n4] =
            *(const float4*)&Wsrc[(size_t)(kbase + k) * C_HID + col0 + n4];
      }
    }
    __syncthreads();
#pragma unroll
    for (int k = 0; k < 32; ++k) {
      const float4 va = *(const float4*)&a_sh[k][tm * 4];
      const float4 vb = *(const float4*)&w_sh[k][tn * 4];
      const float av[4] = {va.x, va.y, va.z, va.w};
      const float bv[4] = {vb.x, vb.y, vb.z, vb.w};
#pragma unroll
      for (int i = 0; i < 4; ++i)
#pragma unroll
        for (int j = 0; j < 4; ++j) acc[i][j] += av[i] * bv[j];
    }
  }
  const int gcol = col0 + tn * 4;
  const float4 b = *(const float4*)&bias[gcol];
  const float bb[4] = {b.x, b.y, b.z, b.w};
#pragma unroll
  for (int i = 0; i < 4; ++i) {
    const int grow = row0 + tm * 4 + i;
    if (grow >= N_NODES) break;
    float4 o;
    o.x = fmaxf(acc[i][0] + bb[0], 0.0f);
    o.y = fmaxf(acc[i][1] + bb[1], 0.0f);
    o.z = fmaxf(acc[i][2] + bb[2], 0.0f);
    o.w = fmaxf(acc[i][3] + bb[3], 0.0f);
    *(float4*)&h[(size_t)grow * C_HID + gcol] = o;
  }
}

// ---------------------------------------------------------------------------
// GEMM on h [N x 256] @ W [256 x 128] -> out [N x 128]
// MODE 0: out = h @ W                    (p = h @ Wl2)
// MODE 1: out = h @ W + aggn + bias      (z = h @ Wr2 + mean-agg + bl2)
// ---------------------------------------------------------------------------
template <int MODE>
__global__ __launch_bounds__(256) void h_gemm(const float* __restrict__ A,
                                              const float* __restrict__ W,
                                              const float* __restrict__ bias,
                                              const float* __restrict__ aggn,
                                              float* __restrict__ out) {
  __shared__ float a_sh[32][68];
  __shared__ float w_sh[32][64];
  const int tid = threadIdx.x;
  const int row0 = blockIdx.x * 64;
  const int col0 = blockIdx.y * 64;
  const int tm = tid >> 4;
  const int tn = tid & 15;
  float acc[4][4] = {};

  for (int kc = 0; kc < 8; ++kc) {
    const int kbase = kc * 32;
    __syncthreads();
    {
      int r = tid >> 3;
      const int k4 = (tid & 7) * 4;
      for (int it = 0; it < 2; ++it, r += 32) {
        const int grow = row0 + r;
        float4 v = make_float4(0.f, 0.f, 0.f, 0.f);
        if (grow < N_NODES)
          v = *(const float4*)&A[(size_t)grow * C_HID + kbase + k4];
        a_sh[k4 + 0][r] = v.x;
        a_sh[k4 + 1][r] = v.y;
        a_sh[k4 + 2][r] = v.z;
        a_sh[k4 + 3][r] = v.w;
      }
    }
    {
      int k = tid >> 4;
      const int n4 = (tid & 15) * 4;
      for (int it = 0; it < 2; ++it, k += 16) {
        *(float4*)&w_sh[k][n4] =
            *(const float4*)&W[(size_t)(kbase + k) * C_OUT + col0 + n4];
      }
    }
    __syncthreads();
#pragma unroll
    for (int k = 0; k < 32; ++k) {
      const float4 va = *(const float4*)&a_sh[k][tm * 4];
      const float4 vb = *(const float4*)&w_sh[k][tn * 4];
      const float av[4] = {va.x, va.y, va.z, va.w};
      const float bv[4] = {vb.x, vb.y, vb.z, vb.w};
#pragma unroll
      for (int i = 0; i < 4; ++i)
#pragma unroll
        for (int j = 0; j < 4; ++j) acc[i][j] += av[i] * bv[j];
    }
  }
  const int gcol = col0 + tn * 4;
  float bb[4] = {0.f, 0.f, 0.f, 0.f};
  if (MODE == 1) {
    const float4 b = *(const float4*)&bias[gcol];
    bb[0] = b.x; bb[1] = b.y; bb[2] = b.z; bb[3] = b.w;
  }
#pragma unroll
  for (int i = 0; i < 4; ++i) {
    const int grow = row0 + tm * 4 + i;
    if (grow >= N_NODES) break;
    float4 o;
    if (MODE == 1) {
      const float4 ag = *(const float4*)&aggn[(size_t)grow * C_OUT + gcol];
      o.x = acc[i][0] + bb[0] + ag.x;
      o.y = acc[i][1] + bb[1] + ag.y;
      o.z = acc[i][2] + bb[2] + ag.z;
      o.w = acc[i][3] + bb[3] + ag.w;
    } else {
      o.x = acc[i][0]; o.y = acc[i][1]; o.z = acc[i][2]; o.w = acc[i][3];
    }
    *(float4*)&out[(size_t)grow * C_OUT + gcol] = o;
  }
}

// ---------------------------------------------------------------------------
// Decode: out[e] = dot(z[lsrc[e]], z[ldst[e]]) over 128 ch. 32 lanes/edge.
// ---------------------------------------------------------------------------
__global__ __launch_bounds__(256) void dot_kernel(const int* __restrict__ ls,
                                                  const int* __restrict__ ld,
                                                  const float* __restrict__ z,
                                                  float* __restrict__ out) {
  long long tid = (long long)blockIdx.x * 256 + threadIdx.x;
  int e = (int)(tid >> 5);
  int lane = (int)(tid & 31);
  if (e >= N_LABEL) return;
  int a = ls[e], b = ld[e];
  const float4 va = *(const float4*)&z[(size_t)a * 128 + lane * 4];
  const float4 vb = *(const float4*)&z[(size_t)b * 128 + lane * 4];
  float p = va.x * vb.x + va.y * vb.y + va.z * vb.z + va.w * vb.w;
  p += __shfl_xor(p, 16, 32);
  p += __shfl_xor(p, 8, 32);
  p += __shfl_xor(p, 4, 32);
  p += __shfl_xor(p, 2, 32);
  p += __shfl_xor(p, 1, 32);
  if (lane == 0) out[e] = p;
}

extern "C" void kernel_launch(void* const* d_in, const int* in_sizes, int n_in,
                              void* d_out, int out_size, void* d_ws, size_t ws_size,
                              hipStream_t stream) {
  const float* x = (const float*)d_in[0];
  const int* ei = (const int*)d_in[1];
  const int* eli = (const int*)d_in[2];
  const float* Wl1 = (const float*)d_in[3];
  const float* bl1 = (const float*)d_in[4];
  const float* Wr1 = (const float*)d_in[5];
  const float* Wl2 = (const float*)d_in[6];
  const float* bl2 = (const float*)d_in[7];
  const float* Wr2 = (const float*)d_in[8];
  float* out = (float*)d_out;

  const int* e_src = ei;
  const int* e_dst = ei + N_EDGES;
  const int* l_src = eli;
  const int* l_dst = eli + N_LABEL;

  char* ws = (char*)d_ws;
  const size_t AGG_BYTES = (size_t)N_NODES * 128 * 4;   //  51.2 MB
  const size_t H_BYTES = (size_t)N_NODES * C_HID * 4;   // 102.4 MB
  const size_t P_BYTES = (size_t)N_NODES * C_OUT * 4;   //  51.2 MB
  const size_t RS_BYTES = (size_t)(N_NODES + 1) * 4;
  float* agg = (float*)ws;
  float* h = (float*)(ws + AGG_BYTES);
  float* p = (float*)(ws + AGG_BYTES + H_BYTES);
  float* z = p;  // z overwrites p (p dead after gather2)
  int* row_start = (int*)(ws + AGG_BYTES + H_BYTES + P_BYTES);
  int* csr_src = (int*)(ws + AGG_BYTES + H_BYTES + P_BYTES + RS_BYTES);
  // counts/cursor alias the (not-yet-live) p region
  int* counts = (int*)p;  // scan converts counts -> cursor in place

  // --- CSR build (by destination) ---
  hipMemsetAsync(counts, 0, (size_t)N_NODES * 4, stream);
  hist_kernel<<<(N_EDGES + 255) / 256, 256, 0, stream>>>(e_dst, counts);
  scan_kernel<<<1, 1024, 0, stream>>>(counts, row_start);
  fill_kernel<<<(N_EDGES + 255) / 256, 256, 0, stream>>>(e_src, e_dst, counts, csr_src);

  // --- layer 1 ---
  gather_mean<<<(N_NODES + 3) / 4, 256, 0, stream>>>(row_start, csr_src, x, agg);
  l1_gemm<<<dim3((N_NODES + 63) / 64, C_HID / 64), 256, 0, stream>>>(
      agg, x, Wl1, Wr1, bl1, h);

  // --- layer 2 (p = h @ Wl2 first, then gather p, then z = h@Wr2 + agg + b) ---
  h_gemm<0><<<dim3((N_NODES + 63) / 64, C_OUT / 64), 256, 0, stream>>>(
      h, Wl2, nullptr, nullptr, p);
  gather_mean<<<(N_NODES + 3) / 4, 256, 0, stream>>>(row_start, csr_src, p, agg);
  h_gemm<1><<<dim3((N_NODES + 63) / 64, C_OUT / 64), 256, 0, stream>>>(
      h, Wr2, bl2, agg, z);

  // --- decode ---
  dot_kernel<<<(int)(((long long)N_LABEL * 32) / 256), 256, 0, stream>>>(
      l_src, l_dst, z, out);
}

// Round 3
// 828.619 us; speedup vs baseline: 7.0681x; 1.2652x over previous
//
#include <hip/hip_runtime.h>

#define N_NODES 100000
#define N_EDGES 1600000
#define N_LABEL 200000
#define C_IN 128
#define C_HID 256
#define C_OUT 128

#define SCAN_NB ((N_NODES + 1023) / 1024)  // 98 blocks, 1024 elems each

// ---------------------------------------------------------------------------
// CSR build step 1: in-degree histogram.
// ---------------------------------------------------------------------------
__global__ __launch_bounds__(256) void hist_kernel(const int* __restrict__ dst,
                                                   int* __restrict__ counts) {
  int e = blockIdx.x * 256 + threadIdx.x;
  if (e < N_EDGES) atomicAdd(&counts[dst[e]], 1);
}

// ---------------------------------------------------------------------------
// Parallel scan, phase 1: per-block sums (1024 elems / block, int4 coalesced).
// ---------------------------------------------------------------------------
__global__ __launch_bounds__(256) void scan_p1(const int* __restrict__ counts,
                                               int* __restrict__ bsum) {
  __shared__ int red[256];
  const int t = threadIdx.x;
  const int idx = blockIdx.x * 1024 + t * 4;
  int s = 0;
  if (idx + 3 < N_NODES) {
    const int4 v = *(const int4*)&counts[idx];
    s = v.x + v.y + v.z + v.w;
  } else {
    for (int j = 0; j < 4 && idx + j < N_NODES; ++j) s += counts[idx + j];
  }
  red[t] = s;
  __syncthreads();
  for (int off = 128; off > 0; off >>= 1) {
    if (t < off) red[t] += red[t + off];
    __syncthreads();
  }
  if (t == 0) bsum[blockIdx.x] = red[0];
}

// ---------------------------------------------------------------------------
// Parallel scan, phase 2: single small block scans the 98 block sums.
// Writes exclusive prefixes bpre[] and the grand total to row_start[N].
// ---------------------------------------------------------------------------
__global__ __launch_bounds__(128) void scan_p2(const int* __restrict__ bsum,
                                               int* __restrict__ bpre,
                                               int* __restrict__ row_start) {
  __shared__ int sh[128];
  const int t = threadIdx.x;
  sh[t] = (t < SCAN_NB) ? bsum[t] : 0;
  __syncthreads();
  for (int off = 1; off < 128; off <<= 1) {
    int v = 0;
    if (t >= off) v = sh[t - off];
    __syncthreads();
    if (t >= off) sh[t] += v;
    __syncthreads();
  }
  if (t < SCAN_NB) bpre[t] = (t == 0) ? 0 : sh[t - 1];
  if (t == SCAN_NB - 1) row_start[N_NODES] = sh[t];
}

// ---------------------------------------------------------------------------
// Parallel scan, phase 3: per-block local exclusive scan + block prefix.
// Writes row_start[i] and overwrites counts[i] in place as the fill cursor.
// ---------------------------------------------------------------------------
__global__ __launch_bounds__(256) void scan_p3(int* __restrict__ counts,
                                               const int* __restrict__ bpre,
                                               int* __restrict__ row_start) {
  __shared__ int sh[256];
  const int t = threadIdx.x;
  const int idx = blockIdx.x * 1024 + t * 4;
  int4 v = make_int4(0, 0, 0, 0);
  const bool full = (idx + 3 < N_NODES);
  if (full) {
    v = *(const int4*)&counts[idx];
  } else {
    if (idx + 0 < N_NODES) v.x = counts[idx + 0];
    if (idx + 1 < N_NODES) v.y = counts[idx + 1];
    if (idx + 2 < N_NODES) v.z = counts[idx + 2];
    if (idx + 3 < N_NODES) v.w = counts[idx + 3];
  }
  const int tsum = v.x + v.y + v.z + v.w;
  sh[t] = tsum;
  __syncthreads();
  for (int off = 1; off < 256; off <<= 1) {
    int u = 0;
    if (t >= off) u = sh[t - off];
    __syncthreads();
    if (t >= off) sh[t] += u;
    __syncthreads();
  }
  int base = bpre[blockIdx.x] + ((t == 0) ? 0 : sh[t - 1]);  // exclusive
  int4 e;
  e.x = base;
  e.y = base + v.x;
  e.z = base + v.x + v.y;
  e.w = base + v.x + v.y + v.z;
  if (full) {
    *(int4*)&row_start[idx] = e;
    *(int4*)&counts[idx] = e;  // cursor
  } else {
    if (idx + 0 < N_NODES) { row_start[idx + 0] = e.x; counts[idx + 0] = e.x; }
    if (idx + 1 < N_NODES) { row_start[idx + 1] = e.y; counts[idx + 1] = e.y; }
    if (idx + 2 < N_NODES) { row_start[idx + 2] = e.z; counts[idx + 2] = e.z; }
    if (idx + 3 < N_NODES) { row_start[idx + 3] = e.w; counts[idx + 3] = e.w; }
  }
}

// ---------------------------------------------------------------------------
// CSR build step 3: fill per-destination source lists.
// ---------------------------------------------------------------------------
__global__ __launch_bounds__(256) void fill_kernel(const int* __restrict__ src,
                                                   const int* __restrict__ dst,
                                                   int* __restrict__ cursor,
                                                   int* __restrict__ csr_src) {
  int e = blockIdx.x * 256 + threadIdx.x;
  if (e < N_EDGES) {
    const int pos = atomicAdd(&cursor[dst[e]], 1);
    csr_src[pos] = src[e];
  }
}

// ---------------------------------------------------------------------------
// Mean aggregation by gather: one 64-lane wave per node; each lane owns 2 of
// the 128 channels (float2). Per edge: one coalesced 512B row read. No atomics.
// ---------------------------------------------------------------------------
__global__ __launch_bounds__(256) void gather_mean(const int* __restrict__ row_start,
                                                   const int* __restrict__ csr_src,
                                                   const float* __restrict__ feat,
                                                   float* __restrict__ out) {
  const int wid = blockIdx.x * 4 + (threadIdx.x >> 6);
  const int lane = threadIdx.x & 63;
  if (wid >= N_NODES) return;
  const int s = row_start[wid];
  const int e = row_start[wid + 1];
  const int c0 = lane * 2;
  float2 acc0 = make_float2(0.f, 0.f);
  float2 acc1 = make_float2(0.f, 0.f);
  int j = s;
  for (; j + 1 < e; j += 2) {
    const int s0 = csr_src[j];
    const int s1 = csr_src[j + 1];
    const float2 v0 = *(const float2*)&feat[(size_t)s0 * 128 + c0];
    const float2 v1 = *(const float2*)&feat[(size_t)s1 * 128 + c0];
    acc0.x += v0.x; acc0.y += v0.y;
    acc1.x += v1.x; acc1.y += v1.y;
  }
  if (j < e) {
    const int s0 = csr_src[j];
    const float2 v0 = *(const float2*)&feat[(size_t)s0 * 128 + c0];
    acc0.x += v0.x; acc0.y += v0.y;
  }
  const float rd = 1.0f / fmaxf((float)(e - s), 1.0f);
  float2 o;
  o.x = (acc0.x + acc1.x) * rd;
  o.y = (acc0.y + acc1.y) * rd;
  *(float2*)&out[(size_t)wid * 128 + c0] = o;
}

// ---------------------------------------------------------------------------
// Layer-1 fused GEMM: h = relu( aggn @ Wl1 + bl1 + x @ Wr1 )
// ---------------------------------------------------------------------------
__global__ __launch_bounds__(256) void l1_gemm(const float* __restrict__ aggn,
                                               const float* __restrict__ x,
                                               const float* __restrict__ Wl,
                                               const float* __restrict__ Wr,
                                               const float* __restrict__ bias,
                                               float* __restrict__ h) {
  __shared__ float a_sh[32][68];
  __shared__ float w_sh[32][64];
  const int tid = threadIdx.x;
  const int row0 = blockIdx.x * 64;
  const int col0 = blockIdx.y * 64;
  const int tm = tid >> 4;
  const int tn = tid & 15;
  float acc[4][4] = {};

  for (int kc = 0; kc < 8; ++kc) {
    const int kk0 = kc * 32;
    const bool first = (kk0 < 128);
    const float* Asrc = first ? aggn : x;
    const float* Wsrc = first ? Wl : Wr;
    const int kbase = first ? kk0 : (kk0 - 128);
    __syncthreads();
    {
      int r = tid >> 3;
      const int k4 = (tid & 7) * 4;
      for (int it = 0; it < 2; ++it, r += 32) {
        const int grow = row0 + r;
        float4 v = make_float4(0.f, 0.f, 0.f, 0.f);
        if (grow < N_NODES)
          v = *(const float4*)&Asrc[(size_t)grow * 128 + kbase + k4];
        a_sh[k4 + 0][r] = v.x;
        a_sh[k4 + 1][r] = v.y;
        a_sh[k4 + 2][r] = v.z;
        a_sh[k4 + 3][r] = v.w;
      }
    }
    {
      int k = tid >> 4;
      const int n4 = (tid & 15) * 4;
      for (int it = 0; it < 2; ++it, k += 16) {
        *(float4*)&w_sh[k][n4] =
            *(const float4*)&Wsrc[(size_t)(kbase + k) * C_HID + col0 + n4];
      }
    }
    __syncthreads();
#pragma unroll
    for (int k = 0; k < 32; ++k) {
      const float4 va = *(const float4*)&a_sh[k][tm * 4];
      const float4 vb = *(const float4*)&w_sh[k][tn * 4];
      const float av[4] = {va.x, va.y, va.z, va.w};
      const float bv[4] = {vb.x, vb.y, vb.z, vb.w};
#pragma unroll
      for (int i = 0; i < 4; ++i)
#pragma unroll
        for (int j = 0; j < 4; ++j) acc[i][j] += av[i] * bv[j];
    }
  }
  const int gcol = col0 + tn * 4;
  const float4 b = *(const float4*)&bias[gcol];
  const float bb[4] = {b.x, b.y, b.z, b.w};
#pragma unroll
  for (int i = 0; i < 4; ++i) {
    const int grow = row0 + tm * 4 + i;
    if (grow >= N_NODES) break;
    float4 o;
    o.x = fmaxf(acc[i][0] + bb[0], 0.0f);
    o.y = fmaxf(acc[i][1] + bb[1], 0.0f);
    o.z = fmaxf(acc[i][2] + bb[2], 0.0f);
    o.w = fmaxf(acc[i][3] + bb[3], 0.0f);
    *(float4*)&h[(size_t)grow * C_HID + gcol] = o;
  }
}

// ---------------------------------------------------------------------------
// GEMM on h [N x 256] @ W [256 x 128] -> out [N x 128]
// MODE 0: out = h @ W                    (p = h @ Wl2)
// MODE 1: out = h @ W + aggn + bias      (z = h @ Wr2 + mean-agg + bl2)
// ---------------------------------------------------------------------------
template <int MODE>
__global__ __launch_bounds__(256) void h_gemm(const float* __restrict__ A,
                                              const float* __restrict__ W,
                                              const float* __restrict__ bias,
                                              const float* __restrict__ aggn,
                                              float* __restrict__ out) {
  __shared__ float a_sh[32][68];
  __shared__ float w_sh[32][64];
  const int tid = threadIdx.x;
  const int row0 = blockIdx.x * 64;
  const int col0 = blockIdx.y * 64;
  const int tm = tid >> 4;
  const int tn = tid & 15;
  float acc[4][4] = {};

  for (int kc = 0; kc < 8; ++kc) {
    const int kbase = kc * 32;
    __syncthreads();
    {
      int r = tid >> 3;
      const int k4 = (tid & 7) * 4;
      for (int it = 0; it < 2; ++it, r += 32) {
        const int grow = row0 + r;
        float4 v = make_float4(0.f, 0.f, 0.f, 0.f);
        if (grow < N_NODES)
          v = *(const float4*)&A[(size_t)grow * C_HID + kbase + k4];
        a_sh[k4 + 0][r] = v.x;
        a_sh[k4 + 1][r] = v.y;
        a_sh[k4 + 2][r] = v.z;
        a_sh[k4 + 3][r] = v.w;
      }
    }
    {
      int k = tid >> 4;
      const int n4 = (tid & 15) * 4;
      for (int it = 0; it < 2; ++it, k += 16) {
        *(float4*)&w_sh[k][n4] =
            *(const float4*)&W[(size_t)(kbase + k) * C_OUT + col0 + n4];
      }
    }
    __syncthreads();
#pragma unroll
    for (int k = 0; k < 32; ++k) {
      const float4 va = *(const float4*)&a_sh[k][tm * 4];
      const float4 vb = *(const float4*)&w_sh[k][tn * 4];
      const float av[4] = {va.x, va.y, va.z, va.w};
      const float bv[4] = {vb.x, vb.y, vb.z, vb.w};
#pragma unroll
      for (int i = 0; i < 4; ++i)
#pragma unroll
        for (int j = 0; j < 4; ++j) acc[i][j] += av[i] * bv[j];
    }
  }
  const int gcol = col0 + tn * 4;
  float bb[4] = {0.f, 0.f, 0.f, 0.f};
  if (MODE == 1) {
    const float4 b = *(const float4*)&bias[gcol];
    bb[0] = b.x; bb[1] = b.y; bb[2] = b.z; bb[3] = b.w;
  }
#pragma unroll
  for (int i = 0; i < 4; ++i) {
    const int grow = row0 + tm * 4 + i;
    if (grow >= N_NODES) break;
    float4 o;
    if (MODE == 1) {
      const float4 ag = *(const float4*)&aggn[(size_t)grow * C_OUT + gcol];
      o.x = acc[i][0] + bb[0] + ag.x;
      o.y = acc[i][1] + bb[1] + ag.y;
      o.z = acc[i][2] + bb[2] + ag.z;
      o.w = acc[i][3] + bb[3] + ag.w;
    } else {
      o.x = acc[i][0]; o.y = acc[i][1]; o.z = acc[i][2]; o.w = acc[i][3];
    }
    *(float4*)&out[(size_t)grow * C_OUT + gcol] = o;
  }
}

// ---------------------------------------------------------------------------
// Decode: out[e] = dot(z[lsrc[e]], z[ldst[e]]) over 128 ch. 32 lanes/edge.
// ---------------------------------------------------------------------------
__global__ __launch_bounds__(256) void dot_kernel(const int* __restrict__ ls,
                                                  const int* __restrict__ ld,
                                                  const float* __restrict__ z,
                                                  float* __restrict__ out) {
  long long tid = (long long)blockIdx.x * 256 + threadIdx.x;
  int e = (int)(tid >> 5);
  int lane = (int)(tid & 31);
  if (e >= N_LABEL) return;
  int a = ls[e], b = ld[e];
  const float4 va = *(const float4*)&z[(size_t)a * 128 + lane * 4];
  const float4 vb = *(const float4*)&z[(size_t)b * 128 + lane * 4];
  float p = va.x * vb.x + va.y * vb.y + va.z * vb.z + va.w * vb.w;
  p += __shfl_xor(p, 16, 32);
  p += __shfl_xor(p, 8, 32);
  p += __shfl_xor(p, 4, 32);
  p += __shfl_xor(p, 2, 32);
  p += __shfl_xor(p, 1, 32);
  if (lane == 0) out[e] = p;
}

extern "C" void kernel_launch(void* const* d_in, const int* in_sizes, int n_in,
                              void* d_out, int out_size, void* d_ws, size_t ws_size,
                              hipStream_t stream) {
  const float* x = (const float*)d_in[0];
  const int* ei = (const int*)d_in[1];
  const int* eli = (const int*)d_in[2];
  const float* Wl1 = (const float*)d_in[3];
  const float* bl1 = (const float*)d_in[4];
  const float* Wr1 = (const float*)d_in[5];
  const float* Wl2 = (const float*)d_in[6];
  const float* bl2 = (const float*)d_in[7];
  const float* Wr2 = (const float*)d_in[8];
  float* out = (float*)d_out;

  const int* e_src = ei;
  const int* e_dst = ei + N_EDGES;
  const int* l_src = eli;
  const int* l_dst = eli + N_LABEL;

  char* ws = (char*)d_ws;
  const size_t AGG_BYTES = (size_t)N_NODES * 128 * 4;   //  51.2 MB
  const size_t H_BYTES = (size_t)N_NODES * C_HID * 4;   // 102.4 MB
  const size_t P_BYTES = (size_t)N_NODES * C_OUT * 4;   //  51.2 MB
  const size_t RS_BYTES = (size_t)(N_NODES + 1) * 4;
  const size_t CSR_BYTES = (size_t)N_EDGES * 4;
  float* agg = (float*)ws;
  float* h = (float*)(ws + AGG_BYTES);
  float* p = (float*)(ws + AGG_BYTES + H_BYTES);
  float* z = p;
  int* row_start = (int*)(ws + AGG_BYTES + H_BYTES + P_BYTES);
  int* csr_src = (int*)(ws + AGG_BYTES + H_BYTES + P_BYTES + RS_BYTES);
  int* bsum = (int*)(ws + AGG_BYTES + H_BYTES + P_BYTES + RS_BYTES + CSR_BYTES);
  int* bpre = bsum + 128;
  int* counts = (int*)p;  // aliases p (dead until fill completes)

  // --- CSR build (by destination) ---
  hipMemsetAsync(counts, 0, (size_t)N_NODES * 4, stream);
  hist_kernel<<<(N_EDGES + 255) / 256, 256, 0, stream>>>(e_dst, counts);
  scan_p1<<<SCAN_NB, 256, 0, stream>>>(counts, bsum);
  scan_p2<<<1, 128, 0, stream>>>(bsum, bpre, row_start);
  scan_p3<<<SCAN_NB, 256, 0, stream>>>(counts, bpre, row_start);
  fill_kernel<<<(N_EDGES + 255) / 256, 256, 0, stream>>>(e_src, e_dst, counts, csr_src);

  // --- layer 1 ---
  gather_mean<<<(N_NODES + 3) / 4, 256, 0, stream>>>(row_start, csr_src, x, agg);
  l1_gemm<<<dim3((N_NODES + 63) / 64, C_HID / 64), 256, 0, stream>>>(
      agg, x, Wl1, Wr1, bl1, h);

  // --- layer 2 ---
  h_gemm<0><<<dim3((N_NODES + 63) / 64, C_OUT / 64), 256, 0, stream>>>(
      h, Wl2, nullptr, nullptr, p);
  gather_mean<<<(N_NODES + 3) / 4, 256, 0, stream>>>(row_start, csr_src, p, agg);
  h_gemm<1><<<dim3((N_NODES + 63) / 64, C_OUT / 64), 256, 0, stream>>>(
      h, Wr2, bl2, agg, z);

  // --- decode ---
  dot_kernel<<<(int)(((long long)N_LABEL * 32) / 256), 256, 0, stream>>>(
      l_src, l_dst, z, out);
}

// Round 4
// 534.080 us; speedup vs baseline: 10.9661x; 1.5515x over previous
//
#include <hip/hip_runtime.h>

#define N_NODES 100000
#define N_EDGES 1600000
#define N_LABEL 200000
#define C_IN 128
#define C_HID 256
#define C_OUT 128

#define SCAN_NB ((N_NODES + 1023) / 1024)  // 98

typedef __attribute__((ext_vector_type(8))) short bf16x8;
typedef __attribute__((ext_vector_type(4))) float f32x4;

__device__ __forceinline__ ushort f2bf(float f) {  // RTNE
  uint u = __float_as_uint(f);
  return (ushort)((u + 0x7fffu + ((u >> 16) & 1u)) >> 16);
}

__device__ __forceinline__ void async_copy16(const void* g, void* lds) {
  __builtin_amdgcn_global_load_lds((const __attribute__((address_space(1))) void*)g,
                                   (__attribute__((address_space(3))) void*)lds,
                                   16, 0, 0);
}

// ---------------------------------------------------------------------------
// CSR build
// ---------------------------------------------------------------------------
__global__ __launch_bounds__(256) void hist_kernel(const int* __restrict__ dst,
                                                   int* __restrict__ counts) {
  int e = blockIdx.x * 256 + threadIdx.x;
  if (e < N_EDGES) atomicAdd(&counts[dst[e]], 1);
}

__global__ __launch_bounds__(256) void scan_p1(const int* __restrict__ counts,
                                               int* __restrict__ bsum) {
  __shared__ int red[256];
  const int t = threadIdx.x;
  const int idx = blockIdx.x * 1024 + t * 4;
  int s = 0;
  if (idx + 3 < N_NODES) {
    const int4 v = *(const int4*)&counts[idx];
    s = v.x + v.y + v.z + v.w;
  } else {
    for (int j = 0; j < 4 && idx + j < N_NODES; ++j) s += counts[idx + j];
  }
  red[t] = s;
  __syncthreads();
  for (int off = 128; off > 0; off >>= 1) {
    if (t < off) red[t] += red[t + off];
    __syncthreads();
  }
  if (t == 0) bsum[blockIdx.x] = red[0];
}

__global__ __launch_bounds__(128) void scan_p2(const int* __restrict__ bsum,
                                               int* __restrict__ bpre,
                                               int* __restrict__ row_start) {
  __shared__ int sh[128];
  const int t = threadIdx.x;
  sh[t] = (t < SCAN_NB) ? bsum[t] : 0;
  __syncthreads();
  for (int off = 1; off < 128; off <<= 1) {
    int v = 0;
    if (t >= off) v = sh[t - off];
    __syncthreads();
    if (t >= off) sh[t] += v;
    __syncthreads();
  }
  if (t < SCAN_NB) bpre[t] = (t == 0) ? 0 : sh[t - 1];
  if (t == SCAN_NB - 1) row_start[N_NODES] = sh[t];
}

__global__ __launch_bounds__(256) void scan_p3(int* __restrict__ counts,
                                               const int* __restrict__ bpre,
                                               int* __restrict__ row_start) {
  __shared__ int sh[256];
  const int t = threadIdx.x;
  const int idx = blockIdx.x * 1024 + t * 4;
  int4 v = make_int4(0, 0, 0, 0);
  const bool full = (idx + 3 < N_NODES);
  if (full) {
    v = *(const int4*)&counts[idx];
  } else {
    if (idx + 0 < N_NODES) v.x = counts[idx + 0];
    if (idx + 1 < N_NODES) v.y = counts[idx + 1];
    if (idx + 2 < N_NODES) v.z = counts[idx + 2];
    if (idx + 3 < N_NODES) v.w = counts[idx + 3];
  }
  const int tsum = v.x + v.y + v.z + v.w;
  sh[t] = tsum;
  __syncthreads();
  for (int off = 1; off < 256; off <<= 1) {
    int u = 0;
    if (t >= off) u = sh[t - off];
    __syncthreads();
    if (t >= off) sh[t] += u;
    __syncthreads();
  }
  int base = bpre[blockIdx.x] + ((t == 0) ? 0 : sh[t - 1]);
  int4 e;
  e.x = base;
  e.y = base + v.x;
  e.z = base + v.x + v.y;
  e.w = base + v.x + v.y + v.z;
  if (full) {
    *(int4*)&row_start[idx] = e;
    *(int4*)&counts[idx] = e;
  } else {
    if (idx + 0 < N_NODES) { row_start[idx + 0] = e.x; counts[idx + 0] = e.x; }
    if (idx + 1 < N_NODES) { row_start[idx + 1] = e.y; counts[idx + 1] = e.y; }
    if (idx + 2 < N_NODES) { row_start[idx + 2] = e.z; counts[idx + 2] = e.z; }
    if (idx + 3 < N_NODES) { row_start[idx + 3] = e.w; counts[idx + 3] = e.w; }
  }
}

__global__ __launch_bounds__(256) void fill_kernel(const int* __restrict__ src,
                                                   const int* __restrict__ dst,
                                                   int* __restrict__ cursor,
                                                   int* __restrict__ csr_src) {
  int e = blockIdx.x * 256 + threadIdx.x;
  if (e < N_EDGES) {
    const int pos = atomicAdd(&cursor[dst[e]], 1);
    csr_src[pos] = src[e];
  }
}

// ---------------------------------------------------------------------------
// fp32 -> bf16 cast (8 elems / thread); n must be divisible by 8.
// ---------------------------------------------------------------------------
__global__ __launch_bounds__(256) void cast_bf16(const float* __restrict__ in,
                                                 ushort* __restrict__ out) {
  const size_t i = ((size_t)blockIdx.x * 256 + threadIdx.x) * 8;
  const float4 a = *(const float4*)&in[i];
  const float4 b = *(const float4*)&in[i + 4];
  uint4 o;
  o.x = (uint)f2bf(a.x) | ((uint)f2bf(a.y) << 16);
  o.y = (uint)f2bf(a.z) | ((uint)f2bf(a.w) << 16);
  o.z = (uint)f2bf(b.x) | ((uint)f2bf(b.y) << 16);
  o.w = (uint)f2bf(b.z) | ((uint)f2bf(b.w) << 16);
  *(uint4*)&out[i] = o;
}

// ---------------------------------------------------------------------------
// Weight prep: WT1[n][k] = bf16(k<128 ? Wl1[k][n] : Wr1[k-128][n])   [256][256]
//              WT2[n][k] = bf16(n<128 ? Wl2[k][n] : Wr2[k][n-128])   [256][256]
// (N-major so MFMA B-fragments are contiguous 16B reads.)
// ---------------------------------------------------------------------------
__global__ __launch_bounds__(256) void prep_wt(const float* __restrict__ Wl1,
                                               const float* __restrict__ Wr1,
                                               const float* __restrict__ Wl2,
                                               const float* __restrict__ Wr2,
                                               ushort* __restrict__ WT1,
                                               ushort* __restrict__ WT2) {
  const int n = blockIdx.x;   // 0..255
  const int k = threadIdx.x;  // 0..255
  const float v1 = (k < 128) ? Wl1[k * 256 + n] : Wr1[(k - 128) * 256 + n];
  WT1[n * 256 + k] = f2bf(v1);
  const float v2 = (n < 128) ? Wl2[k * 128 + n] : Wr2[k * 128 + (n - 128)];
  WT2[n * 256 + k] = f2bf(v2);
}

// ---------------------------------------------------------------------------
// Mean aggregation by gather over bf16 rows (256B), fp32 accumulate.
// MODE 0: write bf16 mean (aggb).  MODE 1: z[wid] += mean (fp32, in place).
// ---------------------------------------------------------------------------
template <int MODE>
__global__ __launch_bounds__(256) void gather_mean_b(const int* __restrict__ row_start,
                                                     const int* __restrict__ csr_src,
                                                     const ushort* __restrict__ feat,
                                                     ushort* __restrict__ bout,
                                                     float* __restrict__ z) {
  const int wid = blockIdx.x * 4 + (threadIdx.x >> 6);
  const int lane = threadIdx.x & 63;
  if (wid >= N_NODES) return;
  const int s = row_start[wid];
  const int e = row_start[wid + 1];
  const int c0 = lane * 2;
  float a0 = 0.f, a1 = 0.f, b0 = 0.f, b1 = 0.f;
  int j = s;
  for (; j + 1 < e; j += 2) {
    const uint v0 = *(const uint*)&feat[(size_t)csr_src[j] * 128 + c0];
    const uint v1 = *(const uint*)&feat[(size_t)csr_src[j + 1] * 128 + c0];
    a0 += __uint_as_float(v0 << 16);
    a1 += __uint_as_float(v0 & 0xffff0000u);
    b0 += __uint_as_float(v1 << 16);
    b1 += __uint_as_float(v1 & 0xffff0000u);
  }
  if (j < e) {
    const uint v0 = *(const uint*)&feat[(size_t)csr_src[j] * 128 + c0];
    a0 += __uint_as_float(v0 << 16);
    a1 += __uint_as_float(v0 & 0xffff0000u);
  }
  const float rd = 1.0f / fmaxf((float)(e - s), 1.0f);
  const float m0 = (a0 + b0) * rd;
  const float m1 = (a1 + b1) * rd;
  if (MODE == 0) {
    *(uint*)&bout[(size_t)wid * 128 + c0] = (uint)f2bf(m0) | ((uint)f2bf(m1) << 16);
  } else {
    float2 zv = *(const float2*)&z[(size_t)wid * 128 + c0];
    zv.x += m0;
    zv.y += m1;
    *(float2*)&z[(size_t)wid * 128 + c0] = zv;
  }
}

// ---------------------------------------------------------------------------
// MFMA GEMM, layer 1: h = relu([aggb|xb] @ [Wl1;Wr1] + bl1), bf16 out.
// 128x128 tile, 4 waves (2x2 of 64x64), BK=32, mfma_f32_16x16x32_bf16.
// A,B staged to linear LDS via global_load_lds (16B lanes).
// ---------------------------------------------------------------------------
__global__ __launch_bounds__(256) void gemm_l1(const ushort* __restrict__ aggb,
                                               const ushort* __restrict__ xb,
                                               const ushort* __restrict__ WT,
                                               const float* __restrict__ bias,
                                               ushort* __restrict__ h) {
  __shared__ ushort As[4096];  // [128 rows][32 k]
  __shared__ ushort Bs[4096];  // [128 ncols][32 k]
  const int tid = threadIdx.x;
  const int w = tid >> 6;
  const int l = tid & 63;
  const int row0 = blockIdx.x * 128;
  const int col0 = blockIdx.y * 128;
  const int wm = (w >> 1) * 64;
  const int wn = (w & 1) * 64;
  const int srow = l >> 2;
  const int sbyte = (l & 3) * 16;
  f32x4 acc[4][4] = {};

  for (int kc = 0; kc < 8; ++kc) {
    const ushort* Ab = (kc < 4) ? aggb : xb;
    const int kco = (kc & 3) * 64;  // byte offset in 256B A row
    const int kbo = kc * 64;        // byte offset in 512B WT row
    __syncthreads();
#pragma unroll
    for (int i = 0; i < 4; ++i) {
      const int c = w * 4 + i;  // 0..15: 0-7 A chunks, 8-15 B chunks
      if (c < 8) {
        int gr = row0 + c * 16 + srow;
        gr = (gr < N_NODES) ? gr : (N_NODES - 1);
        async_copy16((const char*)Ab + (size_t)gr * 256 + kco + sbyte,
                     (char*)As + c * 1024);
      } else {
        const int cb = c - 8;
        const int nr = col0 + cb * 16 + srow;
        async_copy16((const char*)WT + (size_t)nr * 512 + kbo + sbyte,
                     (char*)Bs + cb * 1024);
      }
    }
    __syncthreads();
    const int fr = l & 15;
    const int kg = (l >> 4) * 8;
    bf16x8 af[4], bfr[4];
#pragma unroll
    for (int i = 0; i < 4; ++i)
      af[i] = *(const bf16x8*)&As[(wm + i * 16 + fr) * 32 + kg];
#pragma unroll
    for (int j = 0; j < 4; ++j)
      bfr[j] = *(const bf16x8*)&Bs[(wn + j * 16 + fr) * 32 + kg];
#pragma unroll
    for (int i = 0; i < 4; ++i)
#pragma unroll
      for (int j = 0; j < 4; ++j)
        acc[i][j] = __builtin_amdgcn_mfma_f32_16x16x32_bf16(af[i], bfr[j],
                                                            acc[i][j], 0, 0, 0);
  }

  const int cr = (l >> 4) * 4;
  const int cc = l & 15;
#pragma unroll
  for (int i = 0; i < 4; ++i) {
    const int growb = row0 + wm + i * 16 + cr;
#pragma unroll
    for (int j = 0; j < 4; ++j) {
      const int gcol = col0 + wn + j * 16 + cc;
      const float bv = bias[gcol];
#pragma unroll
      for (int r = 0; r < 4; ++r) {
        const int grow = growb + r;
        if (grow < N_NODES) {
          const float v = fmaxf(acc[i][j][r] + bv, 0.f);
          h[(size_t)grow * 256 + gcol] = f2bf(v);
        }
      }
    }
  }
}

// ---------------------------------------------------------------------------
// MFMA GEMM, layer 2 fused: blockIdx.y==0 -> p = h@Wl2 (bf16)
//                           blockIdx.y==1 -> zp = h@Wr2 + bl2 (fp32)
// Reads h once per y-slice. WT2 = [Wl2^T ; Wr2^T] n-major.
// ---------------------------------------------------------------------------
__global__ __launch_bounds__(256) void gemm_l2(const ushort* __restrict__ h,
                                               const ushort* __restrict__ WT,
                                               const float* __restrict__ bias,
                                               ushort* __restrict__ p,
                                               float* __restrict__ zp) {
  __shared__ ushort As[4096];
  __shared__ ushort Bs[4096];
  const int tid = threadIdx.x;
  const int w = tid >> 6;
  const int l = tid & 63;
  const int row0 = blockIdx.x * 128;
  const int col0 = blockIdx.y * 128;  // selects Wl2^T vs Wr2^T half of WT2
  const int wm = (w >> 1) * 64;
  const int wn = (w & 1) * 64;
  const int srow = l >> 2;
  const int sbyte = (l & 3) * 16;
  f32x4 acc[4][4] = {};

  for (int kc = 0; kc < 8; ++kc) {
    const int kbo = kc * 64;  // byte offset in 512B rows (h and WT2)
    __syncthreads();
#pragma unroll
    for (int i = 0; i < 4; ++i) {
      const int c = w * 4 + i;
      if (c < 8) {
        int gr = row0 + c * 16 + srow;
        gr = (gr < N_NODES) ? gr : (N_NODES - 1);
        async_copy16((const char*)h + (size_t)gr * 512 + kbo + sbyte,
                     (char*)As + c * 1024);
      } else {
        const int cb = c - 8;
        const int nr = col0 + cb * 16 + srow;
        async_copy16((const char*)WT + (size_t)nr * 512 + kbo + sbyte,
                     (char*)Bs + cb * 1024);
      }
    }
    __syncthreads();
    const int fr = l & 15;
    const int kg = (l >> 4) * 8;
    bf16x8 af[4], bfr[4];
#pragma unroll
    for (int i = 0; i < 4; ++i)
      af[i] = *(const bf16x8*)&As[(wm + i * 16 + fr) * 32 + kg];
#pragma unroll
    for (int j = 0; j < 4; ++j)
      bfr[j] = *(const bf16x8*)&Bs[(wn + j * 16 + fr) * 32 + kg];
#pragma unroll
    for (int i = 0; i < 4; ++i)
#pragma unroll
      for (int j = 0; j < 4; ++j)
        acc[i][j] = __builtin_amdgcn_mfma_f32_16x16x32_bf16(af[i], bfr[j],
                                                            acc[i][j], 0, 0, 0);
  }

  const int cr = (l >> 4) * 4;
  const int cc = l & 15;
  const bool is_p = (blockIdx.y == 0);
#pragma unroll
  for (int i = 0; i < 4; ++i) {
    const int growb = row0 + wm + i * 16 + cr;
#pragma unroll
    for (int j = 0; j < 4; ++j) {
      const int gcl = wn + j * 16 + cc;  // 0..127 within output matrix
      const float bv = is_p ? 0.f : bias[gcl];
#pragma unroll
      for (int r = 0; r < 4; ++r) {
        const int grow = growb + r;
        if (grow < N_NODES) {
          const float v = acc[i][j][r] + bv;
          if (is_p)
            p[(size_t)grow * 128 + gcl] = f2bf(v);
          else
            zp[(size_t)grow * 128 + gcl] = v;
        }
      }
    }
  }
}

// ---------------------------------------------------------------------------
// Decode: out[e] = dot(z[lsrc[e]], z[ldst[e]]) over 128 ch. 32 lanes/edge.
// ---------------------------------------------------------------------------
__global__ __launch_bounds__(256) void dot_kernel(const int* __restrict__ ls,
                                                  const int* __restrict__ ld,
                                                  const float* __restrict__ z,
                                                  float* __restrict__ out) {
  long long tid = (long long)blockIdx.x * 256 + threadIdx.x;
  int e = (int)(tid >> 5);
  int lane = (int)(tid & 31);
  if (e >= N_LABEL) return;
  int a = ls[e], b = ld[e];
  const float4 va = *(const float4*)&z[(size_t)a * 128 + lane * 4];
  const float4 vb = *(const float4*)&z[(size_t)b * 128 + lane * 4];
  float p = va.x * vb.x + va.y * vb.y + va.z * vb.z + va.w * vb.w;
  p += __shfl_xor(p, 16, 32);
  p += __shfl_xor(p, 8, 32);
  p += __shfl_xor(p, 4, 32);
  p += __shfl_xor(p, 2, 32);
  p += __shfl_xor(p, 1, 32);
  if (lane == 0) out[e] = p;
}

extern "C" void kernel_launch(void* const* d_in, const int* in_sizes, int n_in,
                              void* d_out, int out_size, void* d_ws, size_t ws_size,
                              hipStream_t stream) {
  const float* x = (const float*)d_in[0];
  const int* ei = (const int*)d_in[1];
  const int* eli = (const int*)d_in[2];
  const float* Wl1 = (const float*)d_in[3];
  const float* bl1 = (const float*)d_in[4];
  const float* Wr1 = (const float*)d_in[5];
  const float* Wl2 = (const float*)d_in[6];
  const float* bl2 = (const float*)d_in[7];
  const float* Wr2 = (const float*)d_in[8];
  float* out = (float*)d_out;

  const int* e_src = ei;
  const int* e_dst = ei + N_EDGES;
  const int* l_src = eli;
  const int* l_dst = eli + N_LABEL;

  char* ws = (char*)d_ws;
  ushort* xb = (ushort*)(ws + 0);                 //  25.6 MB
  ushort* aggb = (ushort*)(ws + 25600000);        //  25.6 MB
  ushort* h = (ushort*)(ws + 51200000);           //  51.2 MB
  ushort* p = (ushort*)(ws + 102400000);          //  25.6 MB
  float* z = (float*)(ws + 128000000);            //  51.2 MB (zp, then z in place)
  ushort* WT1 = (ushort*)(ws + 179200000);        // 128 KB
  ushort* WT2 = (ushort*)(ws + 179331072);        // 128 KB
  int* row_start = (int*)(ws + 179462144);        // 400 KB
  int* csr_src = (int*)(ws + 179862272);          // 6.4 MB
  int* bsum = (int*)(ws + 186262272);
  int* bpre = bsum + 128;
  int* counts = (int*)z;  // aliases z (dead until gemm_l2 writes zp)

  // --- CSR build ---
  hipMemsetAsync(counts, 0, (size_t)N_NODES * 4, stream);
  hist_kernel<<<(N_EDGES + 255) / 256, 256, 0, stream>>>(e_dst, counts);
  scan_p1<<<SCAN_NB, 256, 0, stream>>>(counts, bsum);
  scan_p2<<<1, 128, 0, stream>>>(bsum, bpre, row_start);
  scan_p3<<<SCAN_NB, 256, 0, stream>>>(counts, bpre, row_start);
  fill_kernel<<<(N_EDGES + 255) / 256, 256, 0, stream>>>(e_src, e_dst, counts, csr_src);

  // --- casts / weight prep ---
  cast_bf16<<<(N_NODES * C_IN) / (256 * 8), 256, 0, stream>>>(x, xb);
  prep_wt<<<256, 256, 0, stream>>>(Wl1, Wr1, Wl2, Wr2, WT1, WT2);

  // --- layer 1 ---
  gather_mean_b<0><<<(N_NODES + 3) / 4, 256, 0, stream>>>(row_start, csr_src, xb,
                                                          aggb, nullptr);
  gemm_l1<<<dim3((N_NODES + 127) / 128, 2), 256, 0, stream>>>(aggb, xb, WT1, bl1, h);

  // --- layer 2 ---
  gemm_l2<<<dim3((N_NODES + 127) / 128, 2), 256, 0, stream>>>(h, WT2, bl2, p, z);
  gather_mean_b<1><<<(N_NODES + 3) / 4, 256, 0, stream>>>(row_start, csr_src, p,
                                                          nullptr, z);

  // --- decode ---
  dot_kernel<<<(int)(((long long)N_LABEL * 32) / 256), 256, 0, stream>>>(
      l_src, l_dst, z, out);
}